// Round 11
// baseline (246.996 us; speedup 1.0000x reference)
//
#include <hip/hip_runtime.h>

// SpectralConv2d: B=16, C_in=C_out=64, H=W=256, k=16.
// Retained modes: rows {0..15, 240..255} x cols {0..15} -> direct sparse DFTs.
//
// Pipeline (fp32):
//  k_repack  : R'[c][o][m][wm] scaled weights (coalesced); block 0 also writes
//              cos/sin tables for k_inv
//  k_fwd     : FUSED x-DFT + y-DFT per (b,c). 38 KB LDS -> 4 blocks/CU.
//              Wave-private single-buffer ut (no ut barriers), per-chunk Pl,
//              sincosf seeds, prefetch issued post-consume -> U (no P in HBM)
//  k_cgemm   : per (m,wm): V[b][o] = sum_c U[b][c]*R'[c][o]  (complex)
//  k_inv     : inverse y-DFT (4 quarters/rotation) + x reconstruction -> out

#define B_    16
#define H_    256
#define W_    256

// ws float offsets
#define OFF_CT 0
#define OFF_ST 256
#define OFF_RP 512
#define RP_SZ  (4096*512*2)                  // 4,194,304
#define OFF_U  (OFF_RP + RP_SZ)              // 4,194,816
#define U_SZ   (512*1024*2)                  // 1,048,576
#define OFF_V  (OFF_U + U_SZ)                // 5,243,392

#define UTP   260                            // ut row pitch (floats): conflict-free b128 rows
#define TWOPI_256 0.024543692606170259f      // 2*pi/256

typedef const __attribute__((address_space(1))) void g_void;
typedef __attribute__((address_space(3))) void l_void;

__device__ __forceinline__ void load_lds16(const float* g, float* l) {
    __builtin_amdgcn_global_load_lds((g_void*)g, (l_void*)l, 16, 0, 0);
}

// grid 4096 = (c*64+o); fully coalesced. Block 0 also writes twiddle tables.
__global__ __launch_bounds__(256) void k_repack(const float* __restrict__ wpr,
                                                const float* __restrict__ wpi,
                                                const float* __restrict__ wnr,
                                                const float* __restrict__ wni,
                                                float* __restrict__ ws) {
    int co = blockIdx.x, t = threadIdx.x;      // t = i*16 + wm
    if (co == 0) {
        double a = 2.0 * 3.14159265358979323846 * (double)t / 256.0;
        ws[OFF_CT + t] = (float)cos(a);
        ws[OFF_ST + t] = (float)sin(a);
    }
    int wm = t & 15;
    float norm = (wm == 0 ? 1.f : 2.f) * (1.f / 65536.f);
    size_t src = (size_t)co * 256 + t;
    float2* rp = (float2*)(ws + OFF_RP) + (size_t)co * 512;
    rp[t]       = make_float2(wpr[src] * norm, wpi[src] * norm);   // m = i
    rp[t + 256] = make_float2(wnr[src] * norm, wni[src] * norm);   // m = i+16
}

// FUSED forward. grid 1024 = bc, block 256 = 4 waves, 38 KB LDS (4 blocks/CU).
// Wave w owns rows [8w,8w+8) of each 32-row chunk: stages them itself
// (global_load_lds, single buffer — rows are wave-private so the ch+1 prefetch,
// issued after stage-1 consumed ch, needs no double-buffer and no barrier).
// Stage 1 (per chunk): lane=(r8<<3)|h, row 8w+r8, modes (2h,2h+1), 16 bats x
// 4 ds_read_b128 (conflict-free at pitch 260), quarter-turn + recurrence,
// scalar state. Pl handoff barriered; stage 2: (m1,wm) threads continue the
// 256-step y-DFT recurrence across chunks; write U at end.
__global__ __launch_bounds__(256) void k_fwd(const float* __restrict__ u,
                                             float* __restrict__ U) {
    __shared__ __align__(16) float ut[32][UTP];      // 33.3 KB, wave-private rows
    __shared__ __align__(16) float Pl[32][36];       // per-chunk P, 4.6 KB
    int t = threadIdx.x, bc = blockIdx.x;
    const float* ub = u + (size_t)bc * 65536;
    int lane = t & 63, w = t >> 6;

    // prologue: stage chunk 0 (own rows only)
    #pragma unroll
    for (int k = 0; k < 8; ++k)
        load_lds16(ub + (w * 8 + k) * 256 + lane * 4, &ut[w * 8 + k][0]);

    int h = lane & 7, r8 = lane >> 3;
    int rowc = w * 8 + r8;
    int wm0 = 2 * h, wm1 = wm0 + 1;
    float s0v, c0v, s1v, c1v;
    __sincosf(TWOPI_256 * (float)wm0, &s0v, &c0v);
    __sincosf(TWOPI_256 * (float)wm1, &s1v, &c1v);
    float r0r = c0v, r0i = -s0v;                     // e^{-2pi i wm0/256}
    float r1r = c1v, r1i = -s1v;
    float bs  = (h & 1) ? -1.f : 1.f;                // (-i)^(2h*k) = (-1)^(hk)
    float dsg = (h & 1) ? 1.f : -1.f;                // g1 = c -/+ i d

    // stage-2 mapping: modes f=m1 and f=m1-16
    int wm2 = t & 15, m1 = t >> 4;
    float sv, cv;
    __sincosf(TWOPI_256 * (float)m1, &sv, &cv);
    float q1r = cv, q1i = -sv;                       // e^{-2pi i m1/256}
    __sincosf(TWOPI_256 * (float)(m1 - 16), &sv, &cv);
    float q2r = cv, q2i = -sv;                       // e^{-2pi i (m1-16)/256}
    float w1r = 1.f, w1i = 0.f, w2r = 1.f, w2i = 0.f;
    float U1r = 0.f, U1i = 0.f, U2r = 0.f, U2i = 0.f;

    for (int ch = 0; ch < 8; ++ch) {
        // wait this wave's 8 staging loads (per-wave; no cross-wave dep)
        asm volatile("s_waitcnt vmcnt(0)" ::: "memory");

        // ---- stage 1: stream own row, 2 modes, scalar state only ----
        float p0r = 0.f, p0i = 0.f, p1r = 0.f, p1i = 0.f;
        float t0r = 1.f, t0i = 0.f, t1r = 1.f, t1i = 0.f;
        const float* rowp = &ut[rowc][0];
        #pragma unroll 4
        for (int bat = 0; bat < 16; ++bat) {
            const float* rp = rowp + 4 * bat;
            float4 q0 = *(const float4*)(rp);
            float4 q1 = *(const float4*)(rp + 64);
            float4 q2 = *(const float4*)(rp + 128);
            float4 q3 = *(const float4*)(rp + 192);
            #define PROC_(u0, u1, u2, u3) {                                   \
                float a_ = (u0) + (u2), b_ = (u1) + (u3);                     \
                float c_ = (u0) - (u2), d_ = (u1) - (u3);                     \
                float g0 = fmaf(bs, b_, a_);                                  \
                float g1r = c_, g1i = dsg * d_;                               \
                p0r = fmaf(g0, t0r, p0r);                                     \
                p0i = fmaf(g0, t0i, p0i);                                     \
                p1r = fmaf(g1r, t1r, fmaf(-g1i, t1i, p1r));                   \
                p1i = fmaf(g1r, t1i, fmaf( g1i, t1r, p1i));                   \
                float n0r = t0r * r0r - t0i * r0i;                            \
                float n0i = t0r * r0i + t0i * r0r;                            \
                float n1r = t1r * r1r - t1i * r1i;                            \
                float n1i = t1r * r1i + t1i * r1r;                            \
                t0r = n0r; t0i = n0i; t1r = n1r; t1i = n1i; }
            PROC_(q0.x, q1.x, q2.x, q3.x)
            PROC_(q0.y, q1.y, q2.y, q3.y)
            PROC_(q0.z, q1.z, q2.z, q3.z)
            PROC_(q0.w, q1.w, q2.w, q3.w)
            #undef PROC_
        }

        // prefetch chunk ch+1 into the SAME (wave-private) rows — all ds_reads
        // of chunk ch are consumed above; pin issue order at this point.
        __builtin_amdgcn_sched_barrier(0);
        if (ch < 7) {
            const float* ub2 = ub + (ch + 1) * 8192;
            #pragma unroll
            for (int k = 0; k < 8; ++k)
                load_lds16(ub2 + (w * 8 + k) * 256 + lane * 4, &ut[w * 8 + k][0]);
        }

        // ---- Pl handoff ----
        *(float4*)&Pl[rowc][4 * h] = make_float4(p0r, p0i, p1r, p1i);
        asm volatile("s_waitcnt lgkmcnt(0)" ::: "memory");
        __builtin_amdgcn_s_barrier();                    // Pl visible (no vm drain)

        // ---- stage 2: accumulate 32 y of the y-DFT ----
        #pragma unroll 4
        for (int yy = 0; yy < 32; ++yy) {
            float2 g = *(float2*)&Pl[yy][2 * wm2];
            U1r = fmaf(g.x, w1r, fmaf(-g.y, w1i, U1r));
            U1i = fmaf(g.x, w1i, fmaf( g.y, w1r, U1i));
            U2r = fmaf(g.x, w2r, fmaf(-g.y, w2i, U2r));
            U2i = fmaf(g.x, w2i, fmaf( g.y, w2r, U2i));
            float n1r = w1r * q1r - w1i * q1i, n1i = w1r * q1i + w1i * q1r;
            float n2r = w2r * q2r - w2i * q2i, n2i = w2r * q2i + w2i * q2r;
            w1r = n1r; w1i = n1i; w2r = n2r; w2i = n2i;
        }
        __builtin_amdgcn_s_barrier();                    // Pl free for next chunk
    }

    float2* Ug = (float2*)U;
    Ug[(size_t)(m1 * 16 + wm2) * 1024 + bc]        = make_float2(U1r, U1i);
    Ug[(size_t)((m1 + 16) * 16 + wm2) * 1024 + bc] = make_float2(U2r, U2i);
}

// per-mode channel GEMM: grid 512 = mw
__global__ __launch_bounds__(256) void k_cgemm(float* __restrict__ ws) {
    __shared__ float2 Ul[1024];
    int mw = blockIdx.x, t = threadIdx.x;
    const float2* Ug = (const float2*)(ws + OFF_U) + (size_t)mw * 1024;
    #pragma unroll
    for (int k = 0; k < 4; ++k) Ul[t + 256 * k] = Ug[t + 256 * k];
    __syncthreads();
    int o = t & 63, bq = t >> 6;
    const float2* rp = (const float2*)(ws + OFF_RP);
    float ar[4] = {0.f, 0.f, 0.f, 0.f}, ai[4] = {0.f, 0.f, 0.f, 0.f};
    #pragma unroll 4
    for (int c = 0; c < 64; ++c) {
        float2 R = rp[(size_t)(c * 64 + o) * 512 + mw];
        #pragma unroll
        for (int j = 0; j < 4; ++j) {
            float2 Uv = Ul[(bq * 4 + j) * 64 + c];     // wave-uniform -> broadcast
            ar[j] = fmaf(Uv.x, R.x, fmaf(-Uv.y, R.y, ar[j]));
            ai[j] = fmaf(Uv.x, R.y, fmaf( Uv.y, R.x, ai[j]));
        }
    }
    float2* Vg = (float2*)(ws + OFF_V);
    #pragma unroll
    for (int j = 0; j < 4; ++j)
        Vg[(size_t)((bq * 4 + j) * 64 + o) * 512 + mw] = make_float2(ar[j], ai[j]);
}

// inverse. grid 4096 = (bo, q); block covers y in {q*16+yb + 64g}.
__global__ __launch_bounds__(256) void k_inv(const float* __restrict__ ws,
                                             float* __restrict__ out) {
    __shared__ float Vl[16][68];
    __shared__ float Tl[4][16][36];
    __shared__ float ct[256], st[256];
    int t = threadIdx.x;
    int bo = blockIdx.x >> 2, q = blockIdx.x & 3;
    ct[t] = ws[OFF_CT + t];
    st[t] = ws[OFF_ST + t];
    {
        // V[bo] has 512 complex entries (32 m x 16 wm): load BOTH halves.
        const float2* Vg = (const float2*)(ws + OFF_V) + (size_t)bo * 512;
        float2 v0 = Vg[t];
        float2 v1 = Vg[t + 256];
        int m = t >> 4, wmv = t & 15;
        Vl[wmv][2 * m]        = v0.x;  Vl[wmv][2 * m + 1]        = v0.y;
        Vl[wmv][2 * (m + 16)] = v1.x;  Vl[wmv][2 * (m + 16) + 1] = v1.y;
    }
    __syncthreads();

    // stage 4: T[y0+64g] = sum_m V[m] e^{+2pi i f y0/256} * i^(f g)
    int wm4 = t & 15, yb = t >> 4;
    int y0 = q * 16 + yb;
    float vr[32], vi[32];
    #pragma unroll
    for (int m = 0; m < 32; ++m) { vr[m] = Vl[wm4][2 * m]; vi[m] = Vl[wm4][2 * m + 1]; }
    float cy = ct[y0], sy = st[y0];
    float T0r=0,T0i=0,T1r=0,T1i=0,T2r=0,T2i=0,T3r=0,T3i=0;
    float tr = 1.f, ti = 0.f;
    #pragma unroll
    for (int m = 0; m < 32; ++m) {
        if (m == 16) {
            int i16 = (4096 - 16 * y0) & 255;          // e^{-2pi i 16 y0/256}
            tr = ct[i16]; ti = st[i16];
        }
        float hr = vr[m] * tr - vi[m] * ti;
        float hi = vr[m] * ti + vi[m] * tr;
        const int md = m & 3;
        T0r += hr; T0i += hi;
        if (md == 0)      { T1r += hr; T1i += hi; T2r += hr; T2i += hi; T3r += hr; T3i += hi; }
        else if (md == 1) { T1r -= hi; T1i += hr; T2r -= hr; T2i -= hi; T3r += hi; T3i -= hr; }
        else if (md == 2) { T1r -= hr; T1i -= hi; T2r += hr; T2i += hi; T3r -= hr; T3i -= hi; }
        else              { T1r += hi; T1i -= hr; T2r -= hr; T2i -= hi; T3r -= hi; T3i += hr; }
        float nr = tr * cy - ti * sy, ni = tr * sy + ti * cy;
        tr = nr; ti = ni;
    }
    Tl[0][yb][wm4] = T0r; Tl[0][yb][16 + wm4] = T0i;
    Tl[1][yb][wm4] = T1r; Tl[1][yb][16 + wm4] = T1i;
    Tl[2][yb][wm4] = T2r; Tl[2][yb][16 + wm4] = T2i;
    Tl[3][yb][wm4] = T3r; Tl[3][yb][16 + wm4] = T3i;
    __syncthreads();

    // stage 5: out[y][64k+l] = sum_wm Re{(TR+iTI) e^{+i th wm(l+64k)}}
    int l = t & 63, wv = t >> 6;
    float c0[16], s0[16];
    #pragma unroll
    for (int wm = 0; wm < 16; ++wm) {
        int idx = (wm * l) & 255;
        c0[wm] = ct[idx]; s0[wm] = st[idx];
    }
    float* ob = out + (size_t)bo * 65536;
    for (int yi = 0; yi < 16; ++yi) {
        int y = wv * 64 + q * 16 + yi;
        float TR[16], TI[16];
        const float4* rowv = (const float4*)&Tl[wv][yi][0];
        #pragma unroll
        for (int qq = 0; qq < 4; ++qq) {
            float4 a = rowv[qq];
            TR[4*qq]=a.x; TR[4*qq+1]=a.y; TR[4*qq+2]=a.z; TR[4*qq+3]=a.w;
            float4 b = rowv[qq + 4];
            TI[4*qq]=b.x; TI[4*qq+1]=b.y; TI[4*qq+2]=b.z; TI[4*qq+3]=b.w;
        }
        #pragma unroll
        for (int k = 0; k < 4; ++k) {
            float a = 0.f;
            #pragma unroll
            for (int wm = 0; wm < 16; ++wm) {
                int p = (k * wm) & 3;
                if (p == 0)      a +=  TR[wm] * c0[wm] - TI[wm] * s0[wm];
                else if (p == 1) a += -TR[wm] * s0[wm] - TI[wm] * c0[wm];
                else if (p == 2) a += -TR[wm] * c0[wm] + TI[wm] * s0[wm];
                else             a +=  TR[wm] * s0[wm] + TI[wm] * c0[wm];
            }
            ob[(size_t)y * 256 + 64 * k + l] = a;
        }
    }
}

extern "C" void kernel_launch(void* const* d_in, const int* in_sizes, int n_in,
                              void* d_out, int out_size, void* d_ws, size_t ws_size,
                              hipStream_t stream) {
    const float* u   = (const float*)d_in[0];
    const float* wpr = (const float*)d_in[1];
    const float* wpi = (const float*)d_in[2];
    const float* wnr = (const float*)d_in[3];
    const float* wni = (const float*)d_in[4];
    float* out = (float*)d_out;
    float* ws  = (float*)d_ws;

    hipLaunchKernelGGL(k_repack, dim3(4096), dim3(256), 0, stream, wpr, wpi, wnr, wni, ws);
    hipLaunchKernelGGL(k_fwd,    dim3(1024), dim3(256), 0, stream, u, ws + OFF_U);
    hipLaunchKernelGGL(k_cgemm,  dim3(512),  dim3(256), 0, stream, ws);
    hipLaunchKernelGGL(k_inv,    dim3(4096), dim3(256), 0, stream, ws, out);
}

// Round 12
// 221.649 us; speedup vs baseline: 1.1144x; 1.1144x over previous
//
#include <hip/hip_runtime.h>

// SpectralConv2d: B=16, C_in=C_out=64, H=W=256, k=16.
// Retained modes: rows {0..15, 240..255} x cols {0..15} -> direct sparse DFTs.
//
// Pipeline (fp32):
//  k_fwd1    : x-DFT per (b,c,chunk) [blocks 0..8191]  +  repack R'[mw][co]
//              [blocks 8192..8703] (independent; merged launch).
//  k_fwd2    : y-DFT onto 32 row modes -> U[bc][mw]   (coalesced write)
//  k_cgemm   : per mw: V[mw][bo] = sum_c U[b][c]*R'[c][o] (coalesced R'/V,
//              scattered U reads from L3)
//  k_inv     : inverse y-DFT + x reconstruction -> out (scattered V reads from L3)

#define B_    16
#define H_    256
#define W_    256

// ws float offsets
#define OFF_CT 0
#define OFF_ST 256
#define OFF_RP 512
#define RP_SZ  (512*4096*2)                  // 4,194,304 floats ([mw][co] float2)
#define OFF_U  (OFF_RP + RP_SZ)              // 4,194,816
#define U_SZ   (1024*512*2)                  // 1,048,576 ([bc][mw] float2)
#define OFF_V  (OFF_U + U_SZ)                // 5,243,392 ([mw][bo] float2)

#define UTP   260                            // ut row pitch (floats): conflict-free b128 rows
#define TWOPI_256 0.024543692606170259f      // 2*pi/256

typedef const __attribute__((address_space(1))) void g_void;
typedef __attribute__((address_space(3))) void l_void;

__device__ __forceinline__ void load_lds16(const float* g, float* l) {
    __builtin_amdgcn_global_load_lds((g_void*)g, (l_void*)l, 16, 0, 0);
}

// x-DFT + repack. grid 8704: blocks 0..8191 = (bc,chunk) x-DFT; 8192.. = repack.
// fwd1: wave-private staging (no block barriers), per-wave vmcnt(0), sincosf
// seeds; lane = (r8<<3)|h: row 8w+r8, modes (2h,2h+1); 16 bats x 4
// ds_read_b128 (conflict-free at pitch 260, 8-way broadcast); quarter-turn
// x = j+64k with twiddle(x)=twiddle(j)*(-i)^(wm*k), scalar state.
// repack: block mw writes R'[mw][co] coalesced (scattered reads -> L3).
__global__ __launch_bounds__(256) void k_fwd1(const float* __restrict__ u,
                                              const float* __restrict__ wpr,
                                              const float* __restrict__ wpi,
                                              const float* __restrict__ wnr,
                                              const float* __restrict__ wni,
                                              float* __restrict__ ws,
                                              float* __restrict__ P) {
    __shared__ __align__(16) float ut[32][UTP];      // 33.3 KB
    int t = threadIdx.x;

    if (blockIdx.x >= 8192) {                        // ---- repack branch ----
        int mw = blockIdx.x - 8192;                  // 0..511 = m*16 + wmc
        int m = mw >> 4, wmc = mw & 15;
        const float* wr; const float* wi; int i;
        if (m < 16) { wr = wpr; wi = wpi; i = m; }
        else        { wr = wnr; wi = wni; i = m - 16; }
        if (mw == 0) {                               // twiddle tables for k_inv
            double a = 2.0 * 3.14159265358979323846 * (double)t / 256.0;
            ws[OFF_CT + t] = (float)cos(a);
            ws[OFF_ST + t] = (float)sin(a);
        }
        float norm = (wmc == 0 ? 1.f : 2.f) * (1.f / 65536.f);
        int off = i * 16 + wmc;
        float2* rp = (float2*)(ws + OFF_RP) + (size_t)mw * 4096;
        #pragma unroll
        for (int k = 0; k < 16; ++k) {
            int co = t + 256 * k;
            rp[co] = make_float2(wr[(size_t)co * 256 + off] * norm,
                                 wi[(size_t)co * 256 + off] * norm);
        }
        return;
    }

    int bc = blockIdx.x >> 3, ch = blockIdx.x & 7;
    const float* ub = u + (size_t)bc * 65536 + ch * 8192;
    int lane = t & 63, w = t >> 6;
    #pragma unroll
    for (int k = 0; k < 8; ++k)
        load_lds16(ub + (w * 8 + k) * 256 + lane * 4, &ut[w * 8 + k][0]);

    int h = lane & 7, r8 = lane >> 3;
    int rowc = w * 8 + r8;
    int wm0 = 2 * h, wm1 = wm0 + 1;
    float s0v, c0v, s1v, c1v;
    __sincosf(TWOPI_256 * (float)wm0, &s0v, &c0v);
    __sincosf(TWOPI_256 * (float)wm1, &s1v, &c1v);
    float r0r = c0v, r0i = -s0v;                     // e^{-2pi i wm0/256}
    float r1r = c1v, r1i = -s1v;
    float bs  = (h & 1) ? -1.f : 1.f;                // (-i)^(2h*k) = (-1)^(hk)
    float dsg = (h & 1) ? 1.f : -1.f;                // g1 = c -/+ i d

    float p0r = 0.f, p0i = 0.f, p1r = 0.f, p1i = 0.f;
    float t0r = 1.f, t0i = 0.f, t1r = 1.f, t1i = 0.f;

    // wait ONLY this wave's 8 staging loads; no cross-wave dependency.
    asm volatile("s_waitcnt vmcnt(0)" ::: "memory");

    const float* rowp = &ut[rowc][0];
    #pragma unroll 4
    for (int bat = 0; bat < 16; ++bat) {
        const float* rp = rowp + 4 * bat;
        float4 q0 = *(const float4*)(rp);
        float4 q1 = *(const float4*)(rp + 64);
        float4 q2 = *(const float4*)(rp + 128);
        float4 q3 = *(const float4*)(rp + 192);
        #define PROC_(u0, u1, u2, u3) {                                   \
            float a_ = (u0) + (u2), b_ = (u1) + (u3);                     \
            float c_ = (u0) - (u2), d_ = (u1) - (u3);                     \
            float g0 = fmaf(bs, b_, a_);                                  \
            float g1r = c_, g1i = dsg * d_;                               \
            p0r = fmaf(g0, t0r, p0r);                                     \
            p0i = fmaf(g0, t0i, p0i);                                     \
            p1r = fmaf(g1r, t1r, fmaf(-g1i, t1i, p1r));                   \
            p1i = fmaf(g1r, t1i, fmaf( g1i, t1r, p1i));                   \
            float n0r = t0r * r0r - t0i * r0i;                            \
            float n0i = t0r * r0i + t0i * r0r;                            \
            float n1r = t1r * r1r - t1i * r1i;                            \
            float n1i = t1r * r1i + t1i * r1r;                            \
            t0r = n0r; t0i = n0i; t1r = n1r; t1i = n1i; }
        PROC_(q0.x, q1.x, q2.x, q3.x)
        PROC_(q0.y, q1.y, q2.y, q3.y)
        PROC_(q0.z, q1.z, q2.z, q3.z)
        PROC_(q0.w, q1.w, q2.w, q3.w)
        #undef PROC_
    }
    int y = ch * 32 + rowc;
    ((float4*)P)[((size_t)bc * 256 + y) * 8 + h] = make_float4(p0r, p0i, p1r, p1i);
}

// y-DFT. grid 1024 = bc. y = yy + 64k quarter-turn; md = m1&3 wave-uniform via remap.
// U write coalesced into [bc][mw] layout.
__global__ __launch_bounds__(256) void k_fwd2(const float* __restrict__ P,
                                              float* __restrict__ ws) {
    __shared__ float Pl[256][36];
    int t = threadIdx.x, bc = blockIdx.x;
    const float4* Pg = (const float4*)(P + (size_t)bc * 8192);
    #pragma unroll
    for (int k = 0; k < 8; ++k) {
        int f4 = t + 256 * k;
        int y = f4 >> 3, q = f4 & 7;
        *(float4*)&Pl[y][q * 4] = Pg[f4];
    }
    __syncthreads();

    int wm = t & 15;
    int v  = t >> 4;
    int m1 = ((v & 3) << 2) | (v >> 2);               // md = m1&3 uniform per wave
    float sv, cv;
    __sincosf(TWOPI_256 * (float)m1, &sv, &cv);
    float r1r = cv, r1i = -sv;                        // e^{-2pi i m1/256}
    __sincosf(TWOPI_256 * (float)(m1 - 16), &sv, &cv);
    float r2r = cv, r2i = -sv;                        // e^{-2pi i (m1-16)/256}
    float t1r = 1.f, t1i = 0.f, t2r = 1.f, t2i = 0.f;
    float U1r = 0.f, U1i = 0.f, U2r = 0.f, U2i = 0.f;
    int md = m1 & 3;
    #pragma unroll 4
    for (int yy = 0; yy < 64; ++yy) {
        float2 P0 = *(float2*)&Pl[yy][2 * wm];
        float2 P1 = *(float2*)&Pl[yy + 64][2 * wm];
        float2 P2 = *(float2*)&Pl[yy + 128][2 * wm];
        float2 P3 = *(float2*)&Pl[yy + 192][2 * wm];
        float ar = P0.x + P2.x, ai = P0.y + P2.y;
        float br = P1.x + P3.x, bi = P1.y + P3.y;
        float cr = P0.x - P2.x, ci = P0.y - P2.y;
        float dr = P1.x - P3.x, di = P1.y - P3.y;
        float gr, gi;
        if (md == 0)      { gr = ar + br; gi = ai + bi; }
        else if (md == 1) { gr = cr + di; gi = ci - dr; }   // g = c - i d
        else if (md == 2) { gr = ar - br; gi = ai - bi; }
        else              { gr = cr - di; gi = ci + dr; }   // g = c + i d
        U1r = fmaf(gr, t1r, fmaf(-gi, t1i, U1r));
        U1i = fmaf(gr, t1i, fmaf( gi, t1r, U1i));
        U2r = fmaf(gr, t2r, fmaf(-gi, t2i, U2r));
        U2i = fmaf(gr, t2i, fmaf( gi, t2r, U2i));
        float n1r = t1r * r1r - t1i * r1i, n1i = t1r * r1i + t1i * r1r;
        float n2r = t2r * r2r - t2i * r2i, n2i = t2r * r2i + t2i * r2r;
        t1r = n1r; t1i = n1i; t2r = n2r; t2i = n2i;
    }
    float2* U = (float2*)(ws + OFF_U) + (size_t)bc * 512;   // [bc][mw]
    U[m1 * 16 + wm]          = make_float2(U1r, U1i);       // 128B segments
    U[(m1 + 16) * 16 + wm]   = make_float2(U2r, U2i);
}

// per-mode channel GEMM: grid 512 = mw. U scatter-read (L3), R'/V coalesced.
__global__ __launch_bounds__(256) void k_cgemm(float* __restrict__ ws) {
    __shared__ float2 Ul[1024];
    int mw = blockIdx.x, t = threadIdx.x;
    const float2* Ug = (const float2*)(ws + OFF_U);
    #pragma unroll
    for (int k = 0; k < 4; ++k) {
        int bcv = t + 256 * k;
        Ul[bcv] = Ug[(size_t)bcv * 512 + mw];              // stride-512 scatter (L3)
    }
    __syncthreads();
    int o = t & 63, bq = t >> 6;
    const float2* rp = (const float2*)(ws + OFF_RP) + (size_t)mw * 4096;  // [mw][co]
    float ar[4] = {0.f, 0.f, 0.f, 0.f}, ai[4] = {0.f, 0.f, 0.f, 0.f};
    #pragma unroll 4
    for (int c = 0; c < 64; ++c) {
        float2 R = rp[c * 64 + o];                         // coalesced 512B
        #pragma unroll
        for (int j = 0; j < 4; ++j) {
            float2 Uv = Ul[(bq * 4 + j) * 64 + c];         // wave-uniform -> broadcast
            ar[j] = fmaf(Uv.x, R.x, fmaf(-Uv.y, R.y, ar[j]));
            ai[j] = fmaf(Uv.x, R.y, fmaf( Uv.y, R.x, ai[j]));
        }
    }
    float2* Vg = (float2*)(ws + OFF_V) + (size_t)mw * 1024;  // [mw][bo]
    #pragma unroll
    for (int j = 0; j < 4; ++j)
        Vg[(bq * 4 + j) * 64 + o] = make_float2(ar[j], ai[j]);  // coalesced
}

// inverse. grid 4096 = (bo, q); V scatter-read (L3, 2 loads/thread).
__global__ __launch_bounds__(256) void k_inv(const float* __restrict__ ws,
                                             float* __restrict__ out) {
    __shared__ float Vl[16][68];
    __shared__ float Tl[4][16][36];
    __shared__ float ct[256], st[256];
    int t = threadIdx.x;
    int bo = blockIdx.x >> 2, q = blockIdx.x & 3;
    ct[t] = ws[OFF_CT + t];
    st[t] = ws[OFF_ST + t];
    {
        // V[mw][bo]: thread t loads mw=t and mw=t+256 for this bo.
        const float2* Vg = (const float2*)(ws + OFF_V);
        float2 v0 = Vg[(size_t)t * 1024 + bo];
        float2 v1 = Vg[(size_t)(t + 256) * 1024 + bo];
        int m = t >> 4, wmv = t & 15;
        Vl[wmv][2 * m]        = v0.x;  Vl[wmv][2 * m + 1]        = v0.y;
        Vl[wmv][2 * (m + 16)] = v1.x;  Vl[wmv][2 * (m + 16) + 1] = v1.y;
    }
    __syncthreads();

    // stage 4: T[y0+64g] = sum_m V[m] e^{+2pi i f y0/256} * i^(f g)
    int wm4 = t & 15, yb = t >> 4;
    int y0 = q * 16 + yb;
    float vr[32], vi[32];
    #pragma unroll
    for (int m = 0; m < 32; ++m) { vr[m] = Vl[wm4][2 * m]; vi[m] = Vl[wm4][2 * m + 1]; }
    float cy = ct[y0], sy = st[y0];
    float T0r=0,T0i=0,T1r=0,T1i=0,T2r=0,T2i=0,T3r=0,T3i=0;
    float tr = 1.f, ti = 0.f;
    #pragma unroll
    for (int m = 0; m < 32; ++m) {
        if (m == 16) {
            int i16 = (4096 - 16 * y0) & 255;          // e^{-2pi i 16 y0/256}
            tr = ct[i16]; ti = st[i16];
        }
        float hr = vr[m] * tr - vi[m] * ti;
        float hi = vr[m] * ti + vi[m] * tr;
        const int md = m & 3;
        T0r += hr; T0i += hi;
        if (md == 0)      { T1r += hr; T1i += hi; T2r += hr; T2i += hi; T3r += hr; T3i += hi; }
        else if (md == 1) { T1r -= hi; T1i += hr; T2r -= hr; T2i -= hi; T3r += hi; T3i -= hr; }
        else if (md == 2) { T1r -= hr; T1i -= hi; T2r += hr; T2i += hi; T3r -= hr; T3i -= hi; }
        else              { T1r += hi; T1i -= hr; T2r -= hr; T2i -= hi; T3r -= hi; T3i += hr; }
        float nr = tr * cy - ti * sy, ni = tr * sy + ti * cy;
        tr = nr; ti = ni;
    }
    Tl[0][yb][wm4] = T0r; Tl[0][yb][16 + wm4] = T0i;
    Tl[1][yb][wm4] = T1r; Tl[1][yb][16 + wm4] = T1i;
    Tl[2][yb][wm4] = T2r; Tl[2][yb][16 + wm4] = T2i;
    Tl[3][yb][wm4] = T3r; Tl[3][yb][16 + wm4] = T3i;
    __syncthreads();

    // stage 5: out[y][64k+l] = sum_wm Re{(TR+iTI) e^{+i th wm(l+64k)}}
    int l = t & 63, wv = t >> 6;
    float c0[16], s0[16];
    #pragma unroll
    for (int wm = 0; wm < 16; ++wm) {
        int idx = (wm * l) & 255;
        c0[wm] = ct[idx]; s0[wm] = st[idx];
    }
    float* ob = out + (size_t)bo * 65536;
    for (int yi = 0; yi < 16; ++yi) {
        int y = wv * 64 + q * 16 + yi;
        float TR[16], TI[16];
        const float4* rowv = (const float4*)&Tl[wv][yi][0];
        #pragma unroll
        for (int qq = 0; qq < 4; ++qq) {
            float4 a = rowv[qq];
            TR[4*qq]=a.x; TR[4*qq+1]=a.y; TR[4*qq+2]=a.z; TR[4*qq+3]=a.w;
            float4 b = rowv[qq + 4];
            TI[4*qq]=b.x; TI[4*qq+1]=b.y; TI[4*qq+2]=b.z; TI[4*qq+3]=b.w;
        }
        #pragma unroll
        for (int k = 0; k < 4; ++k) {
            float a = 0.f;
            #pragma unroll
            for (int wm = 0; wm < 16; ++wm) {
                int p = (k * wm) & 3;
                if (p == 0)      a +=  TR[wm] * c0[wm] - TI[wm] * s0[wm];
                else if (p == 1) a += -TR[wm] * s0[wm] - TI[wm] * c0[wm];
                else if (p == 2) a += -TR[wm] * c0[wm] + TI[wm] * s0[wm];
                else             a +=  TR[wm] * s0[wm] + TI[wm] * c0[wm];
            }
            ob[(size_t)y * 256 + 64 * k + l] = a;
        }
    }
}

extern "C" void kernel_launch(void* const* d_in, const int* in_sizes, int n_in,
                              void* d_out, int out_size, void* d_ws, size_t ws_size,
                              hipStream_t stream) {
    const float* u   = (const float*)d_in[0];
    const float* wpr = (const float*)d_in[1];
    const float* wpi = (const float*)d_in[2];
    const float* wnr = (const float*)d_in[3];
    const float* wni = (const float*)d_in[4];
    float* out = (float*)d_out;
    float* ws  = (float*)d_ws;
    float* P   = (float*)d_out;            // 33.5 MB scratch in d_out (overwritten by k_inv)

    hipLaunchKernelGGL(k_fwd1,  dim3(8704), dim3(256), 0, stream, u, wpr, wpi, wnr, wni, ws, P);
    hipLaunchKernelGGL(k_fwd2,  dim3(1024), dim3(256), 0, stream, P, ws);
    hipLaunchKernelGGL(k_cgemm, dim3(512),  dim3(256), 0, stream, ws);
    hipLaunchKernelGGL(k_inv,   dim3(4096), dim3(256), 0, stream, ws, out);
}

// Round 13
// 207.139 us; speedup vs baseline: 1.1924x; 1.0700x over previous
//
#include <hip/hip_runtime.h>

// SpectralConv2d: B=16, C_in=C_out=64, H=W=256, k=16.
// Retained modes: rows {0..15, 240..255} x cols {0..15} -> direct sparse DFTs.
//
// Pipeline (fp32):
//  k_fwd1    : x-DFT per (b,c,chunk) [blocks 0..8191]  +  repack R'[mw][co]
//              [blocks 8192..8703] (independent; merged launch).
//  k_fwd2    : y-DFT onto 32 row modes -> U[bc][mw]   (coalesced write)
//  k_cgemm   : per mw: V[mw][bo] = sum_c U[b][c]*R'[c][o] (coalesced R'/V)
//  k_inv     : inverse y-DFT + quad-symmetric x reconstruction -> out
//              (R13: stage 5 uses {l,128-l,128+l,256-l} shared products: 2x fewer FLOPs)

#define B_    16
#define H_    256
#define W_    256

// ws float offsets
#define OFF_CT 0
#define OFF_ST 256
#define OFF_RP 512
#define RP_SZ  (512*4096*2)                  // 4,194,304 floats ([mw][co] float2)
#define OFF_U  (OFF_RP + RP_SZ)              // 4,194,816
#define U_SZ   (1024*512*2)                  // 1,048,576 ([bc][mw] float2)
#define OFF_V  (OFF_U + U_SZ)                // 5,243,392 ([mw][bo] float2)

#define UTP   260                            // ut row pitch (floats): conflict-free b128 rows
#define TWOPI_256 0.024543692606170259f      // 2*pi/256

typedef const __attribute__((address_space(1))) void g_void;
typedef __attribute__((address_space(3))) void l_void;

__device__ __forceinline__ void load_lds16(const float* g, float* l) {
    __builtin_amdgcn_global_load_lds((g_void*)g, (l_void*)l, 16, 0, 0);
}

// x-DFT + repack. grid 8704: blocks 0..8191 = (bc,chunk) x-DFT; 8192.. = repack.
__global__ __launch_bounds__(256) void k_fwd1(const float* __restrict__ u,
                                              const float* __restrict__ wpr,
                                              const float* __restrict__ wpi,
                                              const float* __restrict__ wnr,
                                              const float* __restrict__ wni,
                                              float* __restrict__ ws,
                                              float* __restrict__ P) {
    __shared__ __align__(16) float ut[32][UTP];      // 33.3 KB
    int t = threadIdx.x;

    if (blockIdx.x >= 8192) {                        // ---- repack branch ----
        int mw = blockIdx.x - 8192;                  // 0..511 = m*16 + wmc
        int m = mw >> 4, wmc = mw & 15;
        const float* wr; const float* wi; int i;
        if (m < 16) { wr = wpr; wi = wpi; i = m; }
        else        { wr = wnr; wi = wni; i = m - 16; }
        if (mw == 0) {                               // twiddle tables for k_inv
            double a = 2.0 * 3.14159265358979323846 * (double)t / 256.0;
            ws[OFF_CT + t] = (float)cos(a);
            ws[OFF_ST + t] = (float)sin(a);
        }
        float norm = (wmc == 0 ? 1.f : 2.f) * (1.f / 65536.f);
        int off = i * 16 + wmc;
        float2* rp = (float2*)(ws + OFF_RP) + (size_t)mw * 4096;
        #pragma unroll
        for (int k = 0; k < 16; ++k) {
            int co = t + 256 * k;
            rp[co] = make_float2(wr[(size_t)co * 256 + off] * norm,
                                 wi[(size_t)co * 256 + off] * norm);
        }
        return;
    }

    int bc = blockIdx.x >> 3, ch = blockIdx.x & 7;
    const float* ub = u + (size_t)bc * 65536 + ch * 8192;
    int lane = t & 63, w = t >> 6;
    #pragma unroll
    for (int k = 0; k < 8; ++k)
        load_lds16(ub + (w * 8 + k) * 256 + lane * 4, &ut[w * 8 + k][0]);

    int h = lane & 7, r8 = lane >> 3;
    int rowc = w * 8 + r8;
    int wm0 = 2 * h, wm1 = wm0 + 1;
    float s0v, c0v, s1v, c1v;
    __sincosf(TWOPI_256 * (float)wm0, &s0v, &c0v);
    __sincosf(TWOPI_256 * (float)wm1, &s1v, &c1v);
    float r0r = c0v, r0i = -s0v;                     // e^{-2pi i wm0/256}
    float r1r = c1v, r1i = -s1v;
    float bs  = (h & 1) ? -1.f : 1.f;                // (-i)^(2h*k) = (-1)^(hk)
    float dsg = (h & 1) ? 1.f : -1.f;                // g1 = c -/+ i d

    float p0r = 0.f, p0i = 0.f, p1r = 0.f, p1i = 0.f;
    float t0r = 1.f, t0i = 0.f, t1r = 1.f, t1i = 0.f;

    // wait ONLY this wave's 8 staging loads; no cross-wave dependency.
    asm volatile("s_waitcnt vmcnt(0)" ::: "memory");

    const float* rowp = &ut[rowc][0];
    #pragma unroll 4
    for (int bat = 0; bat < 16; ++bat) {
        const float* rp = rowp + 4 * bat;
        float4 q0 = *(const float4*)(rp);
        float4 q1 = *(const float4*)(rp + 64);
        float4 q2 = *(const float4*)(rp + 128);
        float4 q3 = *(const float4*)(rp + 192);
        #define PROC_(u0, u1, u2, u3) {                                   \
            float a_ = (u0) + (u2), b_ = (u1) + (u3);                     \
            float c_ = (u0) - (u2), d_ = (u1) - (u3);                     \
            float g0 = fmaf(bs, b_, a_);                                  \
            float g1r = c_, g1i = dsg * d_;                               \
            p0r = fmaf(g0, t0r, p0r);                                     \
            p0i = fmaf(g0, t0i, p0i);                                     \
            p1r = fmaf(g1r, t1r, fmaf(-g1i, t1i, p1r));                   \
            p1i = fmaf(g1r, t1i, fmaf( g1i, t1r, p1i));                   \
            float n0r = t0r * r0r - t0i * r0i;                            \
            float n0i = t0r * r0i + t0i * r0r;                            \
            float n1r = t1r * r1r - t1i * r1i;                            \
            float n1i = t1r * r1i + t1i * r1r;                            \
            t0r = n0r; t0i = n0i; t1r = n1r; t1i = n1i; }
        PROC_(q0.x, q1.x, q2.x, q3.x)
        PROC_(q0.y, q1.y, q2.y, q3.y)
        PROC_(q0.z, q1.z, q2.z, q3.z)
        PROC_(q0.w, q1.w, q2.w, q3.w)
        #undef PROC_
    }
    int y = ch * 32 + rowc;
    ((float4*)P)[((size_t)bc * 256 + y) * 8 + h] = make_float4(p0r, p0i, p1r, p1i);
}

// y-DFT. grid 1024 = bc. y = yy + 64k quarter-turn; md = m1&3 wave-uniform via remap.
__global__ __launch_bounds__(256) void k_fwd2(const float* __restrict__ P,
                                              float* __restrict__ ws) {
    __shared__ float Pl[256][36];
    int t = threadIdx.x, bc = blockIdx.x;
    const float4* Pg = (const float4*)(P + (size_t)bc * 8192);
    #pragma unroll
    for (int k = 0; k < 8; ++k) {
        int f4 = t + 256 * k;
        int y = f4 >> 3, q = f4 & 7;
        *(float4*)&Pl[y][q * 4] = Pg[f4];
    }
    __syncthreads();

    int wm = t & 15;
    int v  = t >> 4;
    int m1 = ((v & 3) << 2) | (v >> 2);               // md = m1&3 uniform per wave
    float sv, cv;
    __sincosf(TWOPI_256 * (float)m1, &sv, &cv);
    float r1r = cv, r1i = -sv;                        // e^{-2pi i m1/256}
    __sincosf(TWOPI_256 * (float)(m1 - 16), &sv, &cv);
    float r2r = cv, r2i = -sv;                        // e^{-2pi i (m1-16)/256}
    float t1r = 1.f, t1i = 0.f, t2r = 1.f, t2i = 0.f;
    float U1r = 0.f, U1i = 0.f, U2r = 0.f, U2i = 0.f;
    int md = m1 & 3;
    #pragma unroll 4
    for (int yy = 0; yy < 64; ++yy) {
        float2 P0 = *(float2*)&Pl[yy][2 * wm];
        float2 P1 = *(float2*)&Pl[yy + 64][2 * wm];
        float2 P2 = *(float2*)&Pl[yy + 128][2 * wm];
        float2 P3 = *(float2*)&Pl[yy + 192][2 * wm];
        float ar = P0.x + P2.x, ai = P0.y + P2.y;
        float br = P1.x + P3.x, bi = P1.y + P3.y;
        float cr = P0.x - P2.x, ci = P0.y - P2.y;
        float dr = P1.x - P3.x, di = P1.y - P3.y;
        float gr, gi;
        if (md == 0)      { gr = ar + br; gi = ai + bi; }
        else if (md == 1) { gr = cr + di; gi = ci - dr; }   // g = c - i d
        else if (md == 2) { gr = ar - br; gi = ai - bi; }
        else              { gr = cr - di; gi = ci + dr; }   // g = c + i d
        U1r = fmaf(gr, t1r, fmaf(-gi, t1i, U1r));
        U1i = fmaf(gr, t1i, fmaf( gi, t1r, U1i));
        U2r = fmaf(gr, t2r, fmaf(-gi, t2i, U2r));
        U2i = fmaf(gr, t2i, fmaf( gi, t2r, U2i));
        float n1r = t1r * r1r - t1i * r1i, n1i = t1r * r1i + t1i * r1r;
        float n2r = t2r * r2r - t2i * r2i, n2i = t2r * r2i + t2i * r2r;
        t1r = n1r; t1i = n1i; t2r = n2r; t2i = n2i;
    }
    float2* U = (float2*)(ws + OFF_U) + (size_t)bc * 512;   // [bc][mw]
    U[m1 * 16 + wm]          = make_float2(U1r, U1i);       // 128B segments
    U[(m1 + 16) * 16 + wm]   = make_float2(U2r, U2i);
}

// per-mode channel GEMM: grid 512 = mw. U scatter-read (L3), R'/V coalesced.
__global__ __launch_bounds__(256) void k_cgemm(float* __restrict__ ws) {
    __shared__ float2 Ul[1024];
    int mw = blockIdx.x, t = threadIdx.x;
    const float2* Ug = (const float2*)(ws + OFF_U);
    #pragma unroll
    for (int k = 0; k < 4; ++k) {
        int bcv = t + 256 * k;
        Ul[bcv] = Ug[(size_t)bcv * 512 + mw];              // stride-512 scatter (L3)
    }
    __syncthreads();
    int o = t & 63, bq = t >> 6;
    const float2* rp = (const float2*)(ws + OFF_RP) + (size_t)mw * 4096;  // [mw][co]
    float ar[4] = {0.f, 0.f, 0.f, 0.f}, ai[4] = {0.f, 0.f, 0.f, 0.f};
    #pragma unroll 4
    for (int c = 0; c < 64; ++c) {
        float2 R = rp[c * 64 + o];                         // coalesced 512B
        #pragma unroll
        for (int j = 0; j < 4; ++j) {
            float2 Uv = Ul[(bq * 4 + j) * 64 + c];         // wave-uniform -> broadcast
            ar[j] = fmaf(Uv.x, R.x, fmaf(-Uv.y, R.y, ar[j]));
            ai[j] = fmaf(Uv.x, R.y, fmaf( Uv.y, R.x, ai[j]));
        }
    }
    float2* Vg = (float2*)(ws + OFF_V) + (size_t)mw * 1024;  // [mw][bo]
    #pragma unroll
    for (int j = 0; j < 4; ++j)
        Vg[(bq * 4 + j) * 64 + o] = make_float2(ar[j], ai[j]);  // coalesced
}

// inverse. grid 4096 = (bo, q). Stage 5 quad-symmetric: lane l covers
// x in {l, 128-l, 128+l, (256-l)&255} from shared products; x=64,192 via
// lane-0 alternating sums. l=0 duplicate writes are benign (sin-sums = 0).
__global__ __launch_bounds__(256) void k_inv(const float* __restrict__ ws,
                                             float* __restrict__ out) {
    __shared__ float Vl[16][68];
    __shared__ float Tl[4][16][36];
    __shared__ float ct[256], st[256];
    int t = threadIdx.x;
    int bo = blockIdx.x >> 2, q = blockIdx.x & 3;
    ct[t] = ws[OFF_CT + t];
    st[t] = ws[OFF_ST + t];
    {
        // V[mw][bo]: thread t loads mw=t and mw=t+256 for this bo.
        const float2* Vg = (const float2*)(ws + OFF_V);
        float2 v0 = Vg[(size_t)t * 1024 + bo];
        float2 v1 = Vg[(size_t)(t + 256) * 1024 + bo];
        int m = t >> 4, wmv = t & 15;
        Vl[wmv][2 * m]        = v0.x;  Vl[wmv][2 * m + 1]        = v0.y;
        Vl[wmv][2 * (m + 16)] = v1.x;  Vl[wmv][2 * (m + 16) + 1] = v1.y;
    }
    __syncthreads();

    // stage 4: T[y0+64g] = sum_m V[m] e^{+2pi i f y0/256} * i^(f g)
    int wm4 = t & 15, yb = t >> 4;
    int y0 = q * 16 + yb;
    float vr[32], vi[32];
    #pragma unroll
    for (int m = 0; m < 32; ++m) { vr[m] = Vl[wm4][2 * m]; vi[m] = Vl[wm4][2 * m + 1]; }
    float cy = ct[y0], sy = st[y0];
    float T0r=0,T0i=0,T1r=0,T1i=0,T2r=0,T2i=0,T3r=0,T3i=0;
    float tr = 1.f, ti = 0.f;
    #pragma unroll
    for (int m = 0; m < 32; ++m) {
        if (m == 16) {
            int i16 = (4096 - 16 * y0) & 255;          // e^{-2pi i 16 y0/256}
            tr = ct[i16]; ti = st[i16];
        }
        float hr = vr[m] * tr - vi[m] * ti;
        float hi = vr[m] * ti + vi[m] * tr;
        const int md = m & 3;
        T0r += hr; T0i += hi;
        if (md == 0)      { T1r += hr; T1i += hi; T2r += hr; T2i += hi; T3r += hr; T3i += hi; }
        else if (md == 1) { T1r -= hi; T1i += hr; T2r -= hr; T2i -= hi; T3r += hi; T3i -= hr; }
        else if (md == 2) { T1r -= hr; T1i -= hi; T2r += hr; T2i += hi; T3r -= hr; T3i -= hi; }
        else              { T1r += hi; T1i -= hr; T2r -= hr; T2i -= hi; T3r -= hi; T3i += hr; }
        float nr = tr * cy - ti * sy, ni = tr * sy + ti * cy;
        tr = nr; ti = ni;
    }
    Tl[0][yb][wm4] = T0r; Tl[0][yb][16 + wm4] = T0i;
    Tl[1][yb][wm4] = T1r; Tl[1][yb][16 + wm4] = T1i;
    Tl[2][yb][wm4] = T2r; Tl[2][yb][16 + wm4] = T2i;
    Tl[3][yb][wm4] = T3r; Tl[3][yb][16 + wm4] = T3i;
    __syncthreads();

    // stage 5: quad-symmetric x reconstruction
    int l = t & 63, wv = t >> 6;
    float c0[16], s0[16];
    #pragma unroll
    for (int wm = 0; wm < 16; ++wm) {
        int idx = (wm * l) & 255;
        c0[wm] = ct[idx]; s0[wm] = st[idx];
    }
    float* ob = out + (size_t)bo * 65536;
    for (int yi = 0; yi < 16; ++yi) {
        int y = wv * 64 + q * 16 + yi;
        float TR[16], TI[16];
        const float4* rowv = (const float4*)&Tl[wv][yi][0];
        #pragma unroll
        for (int qq = 0; qq < 4; ++qq) {
            float4 a = rowv[qq];
            TR[4*qq]=a.x; TR[4*qq+1]=a.y; TR[4*qq+2]=a.z; TR[4*qq+3]=a.w;
            float4 b = rowv[qq + 4];
            TI[4*qq]=b.x; TI[4*qq+1]=b.y; TI[4*qq+2]=b.z; TI[4*qq+3]=b.w;
        }
        // P/Q = even/odd-wm cos-products; R/S = even/odd-wm sin-products
        float Pv = 0.f, Qv = 0.f, Rv = 0.f, Sv = 0.f;
        #pragma unroll
        for (int wm = 0; wm < 16; wm += 2) {
            Pv = fmaf(TR[wm],     c0[wm],     Pv);
            Rv = fmaf(TI[wm],     s0[wm],     Rv);
            Qv = fmaf(TR[wm + 1], c0[wm + 1], Qv);
            Sv = fmaf(TI[wm + 1], s0[wm + 1], Sv);
        }
        float Ac = Pv + Qv, Bs = Rv + Sv;
        float Dc = Pv - Qv, Es = Rv - Sv;
        float* row = ob + (size_t)y * 256;
        row[l]               = Ac - Bs;        // x = l
        row[(256 - l) & 255] = Ac + Bs;        // x = 256-l (l=0: dup of x=0, same value)
        row[128 + l]         = Dc - Es;        // x = 128+l
        row[128 - l]         = Dc + Es;        // x = 128-l (l=0: dup of 128, same value)
        // x = 64, 192: alternating sums (wave-uniform), stored by lane 0
        float E0 = TR[0] + TR[4] + TR[8]  + TR[12];
        float E2 = TR[2] + TR[6] + TR[10] + TR[14];
        float O1 = TI[1] + TI[5] + TI[9]  + TI[13];
        float O3 = TI[3] + TI[7] + TI[11] + TI[15];
        float EC = E0 - E2, OC = O1 - O3;
        if (l == 0) {
            row[64]  = EC - OC;
            row[192] = EC + OC;
        }
    }
}

extern "C" void kernel_launch(void* const* d_in, const int* in_sizes, int n_in,
                              void* d_out, int out_size, void* d_ws, size_t ws_size,
                              hipStream_t stream) {
    const float* u   = (const float*)d_in[0];
    const float* wpr = (const float*)d_in[1];
    const float* wpi = (const float*)d_in[2];
    const float* wnr = (const float*)d_in[3];
    const float* wni = (const float*)d_in[4];
    float* out = (float*)d_out;
    float* ws  = (float*)d_ws;
    float* P   = (float*)d_out;            // 33.5 MB scratch in d_out (overwritten by k_inv)

    hipLaunchKernelGGL(k_fwd1,  dim3(8704), dim3(256), 0, stream, u, wpr, wpi, wnr, wni, ws, P);
    hipLaunchKernelGGL(k_fwd2,  dim3(1024), dim3(256), 0, stream, P, ws);
    hipLaunchKernelGGL(k_cgemm, dim3(512),  dim3(256), 0, stream, ws);
    hipLaunchKernelGGL(k_inv,   dim3(4096), dim3(256), 0, stream, ws, out);
}